// Round 2
// baseline (12495.920 us; speedup 1.0000x reference)
//
#include <hip/hip_runtime.h>

#define BATCH 64
#define SEQ   512
#define INP   512
#define HID   1024
#define MAGIC 0x13570000u

// ============================================================================
// Phase 1: out[m][n] = sum_f X[m][f] * Wih[n][f] + bih[n] + bhh[n]
//   Unchanged: ~200us, near the fp32 vector roofline (219us floor).
// ============================================================================
__global__ __launch_bounds__(256) void xw_gemm(
    const float* __restrict__ X, const float* __restrict__ Wih,
    const float* __restrict__ bih, const float* __restrict__ bhh,
    float* __restrict__ out)
{
    __shared__ float As[8][128];
    __shared__ float Bs[8][128];
    const int t  = threadIdx.x;
    const int m0 = blockIdx.x * 128;
    const int n0 = blockIdx.y * 128;
    const int lr = t >> 1;           // 0..127 tile row for staging
    const int lk = (t & 1) * 4;      // 0 | 4
    const int ty = t >> 4;           // 0..15 (m micro position)
    const int tx = t & 15;           // 0..15 (n micro position)

    float acc[8][8];
#pragma unroll
    for (int i = 0; i < 8; ++i)
#pragma unroll
        for (int j = 0; j < 8; ++j) acc[i][j] = 0.f;

    const float* xrow = X   + (size_t)(m0 + lr) * INP + lk;
    const float* wrow = Wih + (size_t)(n0 + lr) * INP + lk;

    for (int k0 = 0; k0 < INP; k0 += 8) {
        float4 av = *(const float4*)(xrow + k0);
        float4 bv = *(const float4*)(wrow + k0);
        __syncthreads();   // previous tile's compute done before overwrite
        As[lk + 0][lr] = av.x; As[lk + 1][lr] = av.y;
        As[lk + 2][lr] = av.z; As[lk + 3][lr] = av.w;
        Bs[lk + 0][lr] = bv.x; Bs[lk + 1][lr] = bv.y;
        Bs[lk + 2][lr] = bv.z; Bs[lk + 3][lr] = bv.w;
        __syncthreads();
#pragma unroll
        for (int kk = 0; kk < 8; ++kk) {
            float4 a0 = *(const float4*)&As[kk][ty * 4];
            float4 a1 = *(const float4*)&As[kk][64 + ty * 4];
            float4 b0 = *(const float4*)&Bs[kk][tx * 4];
            float4 b1 = *(const float4*)&Bs[kk][64 + tx * 4];
            float am[8] = {a0.x, a0.y, a0.z, a0.w, a1.x, a1.y, a1.z, a1.w};
            float bn[8] = {b0.x, b0.y, b0.z, b0.w, b1.x, b1.y, b1.z, b1.w};
#pragma unroll
            for (int i = 0; i < 8; ++i)
#pragma unroll
                for (int j = 0; j < 8; ++j)
                    acc[i][j] = fmaf(am[i], bn[j], acc[i][j]);
        }
    }

    const int nA = n0 + tx * 4;
    const int nB = n0 + 64 + tx * 4;
    float4 bA1 = *(const float4*)(bih + nA);
    float4 bA2 = *(const float4*)(bhh + nA);
    float4 bB1 = *(const float4*)(bih + nB);
    float4 bB2 = *(const float4*)(bhh + nB);
    float4 biasA = make_float4(bA1.x + bA2.x, bA1.y + bA2.y, bA1.z + bA2.z, bA1.w + bA2.w);
    float4 biasB = make_float4(bB1.x + bB2.x, bB1.y + bB2.y, bB1.z + bB2.z, bB1.w + bB2.w);

#pragma unroll
    for (int i = 0; i < 8; ++i) {
        int mloc = (i < 4) ? (ty * 4 + i) : (64 + ty * 4 + (i - 4));
        size_t m = (size_t)(m0 + mloc);
        float4 vA = make_float4(acc[i][0] + biasA.x, acc[i][1] + biasA.y,
                                acc[i][2] + biasA.z, acc[i][3] + biasA.w);
        float4 vB = make_float4(acc[i][4] + biasB.x, acc[i][5] + biasB.y,
                                acc[i][6] + biasB.z, acc[i][7] + biasB.w);
        *(float4*)(out + m * HID + nA) = vA;
        *(float4*)(out + m * HID + nB) = vB;
    }
}

// ============================================================================
// Phase 2 v3: persistent sequential scan, in-place on out.
// 256 blocks = 4 batch-groups (16 batches) x 64 j-tiles (16 j), 512 threads.
// vs v1 (last passing version):
//   - h[s-1] staged into 64KB LDS by one coalesced 8xfloat4-per-thread burst
//     (replaces 256 latency-strung global b128 loads per lane, which the
//     agent-acquire fence forced to L3/HBM latency with 1 wave/SIMD of TLP).
//   - Hlds XOR-swizzled: logical col c stored at c ^ ((c>>5)&7) so the 8
//     kc-groups' broadcast reads hit 8 distinct bank-groups (else 8-way).
//   - W tile held in REGISTERS (32 float4/lane, loop-invariant): removes the
//     per-iter 1KB/wave LDS W-gather entirely. No Wlds -> 64KB static LDS only.
//   - 512 threads / 8 waves: k split 8-way (shfl_xor 8/16/32 reduce),
//     2 waves/SIMD for latency hiding.
//   - epilogue parallel: 32 lanes/wave do exactly one tanh+store each.
//   - xw operand prefetched at loop top (phase-1 data, only ever written by
//     this same thread at step s), hidden under the flag poll.
// vs v2 (container-killer): NO hipFuncSetAttribute, NO dynamic LDS.
// Sync scheme (magic flags, slots mod 8, agent scope) unchanged from v1.
// ============================================================================
__global__ __launch_bounds__(512) void rnn_scan(
    const float* __restrict__ Whh, float* __restrict__ out,
    unsigned* __restrict__ flags)
{
    __shared__ float4 Hlds[16][256];   // 64 KB static; col-swizzled (see above)

    const int t  = threadIdx.x;        // 0..511
    const int g  = blockIdx.x >> 6;    // batch group 0..3
    const int jt = blockIdx.x & 63;    // j tile 0..63

    const int lane = t & 63;
    const int w    = t >> 6;           // wave 0..7
    const int bq   = w >> 1;           // batch quad 0..3
    const int jh   = w & 1;            // j half 0..1
    const int kc   = lane >> 3;        // k chunk 0..7 (128 k = 32 f4 each)
    const int jl   = lane & 7;         // j within half
    const int row  = jh * 8 + jl;      // W row / j within tile, 0..15
    const int b4   = bq * 4;           // first batch (group-relative) of quad
    const int Lb   = kc * 32;          // f4 column base for this lane's chunk

    // ---- W fragment -> registers (one-time, loop-invariant, 128 VGPR) ----
    float4 wreg[32];
    {
        const float4* wsrc =
            (const float4*)(Whh + (size_t)(jt * 16 + row) * HID) + (size_t)Lb;
#pragma unroll
        for (int i = 0; i < 32; ++i) wreg[i] = wsrc[i];
    }

    // epilogue roles: lanes 0..31 of each wave, one (batch, j) value each
    const bool act = (lane < 32);
    const int  q   = kc & 3;           // batch within quad (lanes<32: q==kc)
    float* outp = out + ((size_t)(g * 16 + b4 + q) * SEQ) * HID + (jt * 16 + row);

    const float4* h0p = &Hlds[b4 + 0][Lb];
    const float4* h1p = &Hlds[b4 + 1][Lb];
    const float4* h2p = &Hlds[b4 + 2][Lb];
    const float4* h3p = &Hlds[b4 + 3][Lb];

    __syncthreads();

    for (int s = 0; s < SEQ; ++s) {
        // prefetch xw (written by phase 1; only this thread ever rewrites it,
        // at step s below). Latency hides under the flag poll.
        float xwv = 0.f;
        if (act) xwv = outp[(size_t)s * HID];

        float a0 = 0.f, a1 = 0.f, a2 = 0.f, a3 = 0.f;

        if (s > 0) {
            // ---- group barrier: all 64 j-tiles of group g finished s-1 ----
            if (t < 64) {
                const unsigned want = MAGIC + (unsigned)(s - 1);
                unsigned* f = flags + ((((s - 1) & 7) * 4 + g) * 64 + t);
                while (__hip_atomic_load(f, __ATOMIC_RELAXED, __HIP_MEMORY_SCOPE_AGENT) != want)
                    __builtin_amdgcn_s_sleep(1);
            }
            __syncthreads();
            __builtin_amdgcn_fence(__ATOMIC_ACQUIRE, "agent");  // kill stale cache

            // ---- stage h[s-1] for the group's 16 batches: 64KB coalesced ----
            {
                const float* hb = out + ((size_t)(g * 16) * SEQ + (s - 1)) * HID;
                float4 tmp[8];
#pragma unroll
                for (int i = 0; i < 8; ++i) {
                    int idx = i * 512 + t;            // 0..4095 f4 slots
                    tmp[i] = *(const float4*)(hb + (size_t)(idx >> 8) * (SEQ * HID)
                                                 + (size_t)(idx & 255) * 4);
                }
#pragma unroll
                for (int i = 0; i < 8; ++i) {
                    int idx = i * 512 + t;
                    int c   = idx & 255;
                    Hlds[idx >> 8][c ^ ((c >> 5) & 7)] = tmp[i];  // XOR swizzle
                }
            }
            __syncthreads();

            // ---- compute: 32 f4-iters, 16 fma each; swizzle-corrected reads
            //      (logical col kc*32+i lives at physical kc*32 + (i^kc)) ----
#pragma unroll
            for (int i = 0; i < 32; ++i) {
                const float4 w4 = wreg[i];
                const int sc = i ^ kc;
                const float4 x0 = h0p[sc];
                const float4 x1 = h1p[sc];
                const float4 x2 = h2p[sc];
                const float4 x3 = h3p[sc];
                a0 = fmaf(x0.x, w4.x, a0); a0 = fmaf(x0.y, w4.y, a0);
                a0 = fmaf(x0.z, w4.z, a0); a0 = fmaf(x0.w, w4.w, a0);
                a1 = fmaf(x1.x, w4.x, a1); a1 = fmaf(x1.y, w4.y, a1);
                a1 = fmaf(x1.z, w4.z, a1); a1 = fmaf(x1.w, w4.w, a1);
                a2 = fmaf(x2.x, w4.x, a2); a2 = fmaf(x2.y, w4.y, a2);
                a2 = fmaf(x2.z, w4.z, a2); a2 = fmaf(x2.w, w4.w, a2);
                a3 = fmaf(x3.x, w4.x, a3); a3 = fmaf(x3.y, w4.y, a3);
                a3 = fmaf(x3.z, w4.z, a3); a3 = fmaf(x3.w, w4.w, a3);
            }
            // ---- reduce k-chunk partials (kc = lane bits 3..5) ----
            a0 += __shfl_xor(a0, 8); a0 += __shfl_xor(a0, 16); a0 += __shfl_xor(a0, 32);
            a1 += __shfl_xor(a1, 8); a1 += __shfl_xor(a1, 16); a1 += __shfl_xor(a1, 32);
            a2 += __shfl_xor(a2, 8); a2 += __shfl_xor(a2, 16); a2 += __shfl_xor(a2, 32);
            a3 += __shfl_xor(a3, 8); a3 += __shfl_xor(a3, 16); a3 += __shfl_xor(a3, 32);
        }

        // ---- finalize: 32 lanes/wave, one tanh + one agent store each ----
        if (act) {
            float v = (q == 0) ? a0 : (q == 1) ? a1 : (q == 2) ? a2 : a3;
            v = tanhf(xwv + v);
            __hip_atomic_store(outp + (size_t)s * HID, v,
                               __ATOMIC_RELAXED, __HIP_MEMORY_SCOPE_AGENT);
        }
        __syncthreads();   // drains vmcnt(0): all block stores globally visible
        if (t == 0)
            __hip_atomic_store(flags + (((s & 7) * 4 + g) * 64 + jt),
                               MAGIC + (unsigned)s,
                               __ATOMIC_RELAXED, __HIP_MEMORY_SCOPE_AGENT);
    }
}

// ============================================================================
extern "C" void kernel_launch(void* const* d_in, const int* in_sizes, int n_in,
                              void* d_out, int out_size, void* d_ws, size_t ws_size,
                              hipStream_t stream)
{
    (void)in_sizes; (void)n_in; (void)out_size; (void)ws_size;
    const float* x   = (const float*)d_in[0];   // (64,512,512)
    const float* Wih = (const float*)d_in[1];   // (1024,512)
    const float* Whh = (const float*)d_in[2];   // (1024,1024)
    const float* bih = (const float*)d_in[3];   // (1024,)
    const float* bhh = (const float*)d_in[4];   // (1024,)
    float* out = (float*)d_out;                 // (64,512,1024)
    unsigned* flags = (unsigned*)d_ws;          // 8 KB of flag slots (poison-safe)

    dim3 g1(BATCH * SEQ / 128, HID / 128);      // (256, 8)
    xw_gemm<<<g1, 256, 0, stream>>>(x, Wih, bih, bhh, out);
    rnn_scan<<<256, 512, 0, stream>>>(Whh, out, flags);
}